// Round 6
// baseline (928.714 us; speedup 1.0000x reference)
//
#include <hip/hip_runtime.h>
#include <math.h>

#define NNODES  200000
#define NEDGES  6400000
#define NGRAPHS 512
#define FIN     92
#define WID     10
#define HPAD    16                     // hs row padded to 16 floats (64 B)
#define NBLK    ((NNODES + 255) / 256) // 782

// partition geometry
#define LBITS   10
#define LSIZE   1024                   // dst nodes per bucket
#define LMASK   (LSIZE - 1)
#define NB      196                    // ceil(200000/1024) dst buckets
#define CHBITS  14
#define NCHK    13                     // ceil(200000/16384) src chunks
#define DCELLS  (NB * NCHK)            // 2548 dst-plane cells
#define CELLS   (DCELLS + NB)          // + 196 src-plane cells = 2744
#define PBLK    512                    // partition blocks
#define EPB     (NEDGES / PBLK)        // 12500 edges per partition block (exact)
#define CNT_N   (CELLS * PBLK)         // 1,404,928 scan elements
#define SBLKS   (CNT_N / 256)          // 5488 scan blocks (exact)
#define SBASE   (DCELLS * PBLK)        // index of first src-plane element

// ---------------------------------------------------------------------------
// P1: per-(cell,block) counts via LDS histograms. ZERO global atomics.
// dst-plane cell = dstBucket*NCHK + srcChunk  (chunk-minor => CSR rows come
// out src-chunk-ordered => k_agg1's gather window is L2-resident).
// Output layout is k-major (cntT[k*CELLS + cell]) for coalesced writes; a
// transpose converts to the cell-major scan layout.
// ---------------------------------------------------------------------------
__global__ void k_part_count(const int* __restrict__ src,
                             const int* __restrict__ dst,
                             int* __restrict__ cntT) {
    __shared__ int hD[DCELLS];
    __shared__ int hS[NB];
    int tid = threadIdx.x, k = blockIdx.x;
    for (int j = tid; j < DCELLS; j += 256) hD[j] = 0;
    if (tid < NB) hS[tid] = 0;
    __syncthreads();
    int base = k * EPB;
    for (int i = tid; i < EPB; i += 256) {
        int e = base + i;
        int s = src[e];
        int d = dst[e];
        atomicAdd(&hD[(d >> LBITS) * NCHK + (s >> CHBITS)], 1);
        atomicAdd(&hS[s >> LBITS], 1);
    }
    __syncthreads();
    for (int j = tid; j < CELLS; j += 256)
        cntT[k * CELLS + j] = (j < DCELLS) ? hD[j] : hS[j - DCELLS];
}

// ---------------------------------------------------------------------------
// LDS-tiled transpose: out[c*R + r] = in[r*C + c]. block (32,8).
// ---------------------------------------------------------------------------
__global__ void k_transpose(const int* __restrict__ in, int* __restrict__ out,
                            int R, int C) {
    __shared__ int tile[32][33];
    int bx = blockIdx.x * 32, by = blockIdx.y * 32;
#pragma unroll
    for (int i = 0; i < 32; i += 8) {
        int rr = by + threadIdx.y + i, cc = bx + threadIdx.x;
        if (rr < R && cc < C) tile[threadIdx.y + i][threadIdx.x] = in[rr * C + cc];
    }
    __syncthreads();
#pragma unroll
    for (int i = 0; i < 32; i += 8) {
        int rr = bx + threadIdx.y + i, cc = by + threadIdx.x;
        if (rr < C && cc < R) out[rr * R + cc] = tile[threadIdx.x][threadIdx.y + i];
    }
}

// ---------------------------------------------------------------------------
// Scan step 1: per-block (256-elem) partial sums of cnt (cell-major layout)
// ---------------------------------------------------------------------------
__global__ void k_scan_partial(const int* __restrict__ cnt,
                               int* __restrict__ partial) {
    __shared__ int sdata[256];
    int tid = threadIdx.x;
    sdata[tid] = cnt[blockIdx.x * 256 + tid];
    __syncthreads();
    for (int s = 128; s > 0; s >>= 1) {
        if (tid < s) sdata[tid] += sdata[tid + s];
        __syncthreads();
    }
    if (tid == 0) partial[blockIdx.x] = sdata[0];
}

// ---------------------------------------------------------------------------
// Scan step 2: single-block exclusive scan of the 5488 partials (chunked)
// ---------------------------------------------------------------------------
__global__ void k_scan_top(int* __restrict__ partial) {
    __shared__ int buf[1024];
    __shared__ int carry_s;
    if (threadIdx.x == 0) carry_s = 0;
    __syncthreads();
    for (int base = 0; base < SBLKS; base += 1024) {
        int i = base + threadIdx.x;
        int c = carry_s;
        int orig = (i < SBLKS) ? partial[i] : 0;
        buf[threadIdx.x] = orig;
        __syncthreads();
        for (int off = 1; off < 1024; off <<= 1) {
            int t = (threadIdx.x >= off) ? buf[threadIdx.x - off] : 0;
            __syncthreads();
            buf[threadIdx.x] += t;
            __syncthreads();
        }
        if (i < SBLKS) partial[i] = buf[threadIdx.x] - orig + c;
        __syncthreads();
        if (threadIdx.x == 0) carry_s = c + buf[1023];
        __syncthreads();
    }
}

// ---------------------------------------------------------------------------
// Scan step 3: apply -- in-place exclusive scan of cnt
// ---------------------------------------------------------------------------
__global__ void k_scan_apply(int* __restrict__ cnt,
                             const int* __restrict__ partial) {
    __shared__ int buf[256];
    int tid = threadIdx.x;
    int i = blockIdx.x * 256 + tid;
    int v = cnt[i];
    buf[tid] = v;
    __syncthreads();
    for (int off = 1; off < 256; off <<= 1) {
        int t = (tid >= off) ? buf[tid - off] : 0;
        __syncthreads();
        buf[tid] += t;
        __syncthreads();
    }
    cnt[i] = buf[tid] - v + partial[blockIdx.x];
}

// ---------------------------------------------------------------------------
// P2: scatter edges into (bucket x chunk) cells. LDS cursors seeded from the
// back-transposed scanned bases -- ZERO global atomics, coalesced base loads.
//   dstpart[pos] = (w, src<<10 | dst&1023)
//   srcpart[pos] = src & 1023
// ---------------------------------------------------------------------------
__global__ void k_part_scatter(const float* __restrict__ r,
                               const int* __restrict__ src,
                               const int* __restrict__ dst,
                               const int* __restrict__ cntT,
                               float2* __restrict__ dstpart,
                               unsigned short* __restrict__ srcpart) {
    __shared__ int curD[DCELLS];
    __shared__ int curS[NB];
    int tid = threadIdx.x, k = blockIdx.x;
    for (int j = tid; j < CELLS; j += 256) {
        int v = cntT[k * CELLS + j];
        if (j < DCELLS) curD[j] = v;
        else curS[j - DCELLS] = v - NEDGES;
    }
    __syncthreads();
    int base = k * EPB;
    for (int i = tid; i < EPB; i += 256) {
        int e = base + i;
        float x = r[3 * e + 0];
        float y = r[3 * e + 1];
        float z = r[3 * e + 2];
        float w = expf(-(x * x + y * y + z * z));
        int s = src[e];
        int d = dst[e];
        int pd = atomicAdd(&curD[(d >> LBITS) * NCHK + (s >> CHBITS)], 1);
        dstpart[pd] = make_float2(w, __int_as_float((s << LBITS) | (d & LMASK)));
        int ps = atomicAdd(&curS[s >> LBITS], 1);
        srcpart[ps] = (unsigned short)(s & LMASK);
    }
}

// ---------------------------------------------------------------------------
// P3s: per-bucket out-degree histogram (LDS) -> inv_sqrt_out.
// Runs BEFORE k_bucket_csr because srcpart aliases the csr region.
// ---------------------------------------------------------------------------
__global__ void k_bucket_odeg(const unsigned short* __restrict__ srcpart,
                              const int* __restrict__ cnt,
                              float* __restrict__ inv_out) {
    __shared__ int hist[LSIZE];
    int tid = threadIdx.x, b = blockIdx.x;
    int bstart = cnt[SBASE + b * PBLK] - NEDGES;
    int bend = (b == NB - 1) ? NEDGES : (cnt[SBASE + (b + 1) * PBLK] - NEDGES);
    for (int l = tid; l < LSIZE; l += 256) hist[l] = 0;
    __syncthreads();
    for (int p = bstart + tid; p < bend; p += 256)
        atomicAdd(&hist[srcpart[p]], 1);
    __syncthreads();
    for (int l = tid; l < LSIZE; l += 256) {
        int n = (b << LBITS) + l;
        if (n < NNODES) {
            int c = hist[l];
            inv_out[n] = rsqrtf((float)(c < 1 ? 1 : c));
        }
    }
}

// ---------------------------------------------------------------------------
// P3d: per-bucket exact CSR build. Bucket segment is chunk-ordered; cursor
// placement preserves that order within each row -> rows ~src-sorted.
// ---------------------------------------------------------------------------
__global__ void k_bucket_csr(const float2* __restrict__ dstpart,
                             const int* __restrict__ cnt,
                             float2* __restrict__ csr,
                             int* __restrict__ row_ptr,
                             float* __restrict__ inv_in) {
    __shared__ int hist[LSIZE];
    __shared__ int offl[LSIZE];
    __shared__ int sbuf[256];
    int tid = threadIdx.x, b = blockIdx.x;
    int bstart = cnt[(b * NCHK) * PBLK];
    int bend = cnt[((b + 1) * NCHK) * PBLK];  // b==NB-1 reads cnt[SBASE]==NEDGES

    for (int l = tid; l < LSIZE; l += 256) hist[l] = 0;
    __syncthreads();
    for (int p = bstart + tid; p < bend; p += 256) {
        float2 rec = dstpart[p];
        atomicAdd(&hist[__float_as_uint(rec.y) & LMASK], 1);
    }
    __syncthreads();

    // exclusive scan of the 1024 counters (4 per thread + block scan)
    int t4 = tid * 4;
    int h0 = hist[t4], h1 = hist[t4 + 1], h2 = hist[t4 + 2], h3 = hist[t4 + 3];
    int tot = h0 + h1 + h2 + h3;
    sbuf[tid] = tot;
    __syncthreads();
    for (int off = 1; off < 256; off <<= 1) {
        int t = (tid >= off) ? sbuf[tid - off] : 0;
        __syncthreads();
        sbuf[tid] += t;
        __syncthreads();
    }
    int ex = sbuf[tid] - tot;
    offl[t4] = ex;
    offl[t4 + 1] = ex + h0;
    offl[t4 + 2] = ex + h0 + h1;
    offl[t4 + 3] = ex + h0 + h1 + h2;
    __syncthreads();

    for (int l = tid; l < LSIZE; l += 256) {
        int c = hist[l];
        int rp = bstart + offl[l];
        int n = (b << LBITS) + l;
        if (n < NNODES) {
            row_ptr[n] = rp;
            inv_in[n] = rsqrtf((float)(c < 1 ? 1 : c));
        }
        hist[l] = rp;  // global cursor
    }
    __syncthreads();

    for (int p = bstart + tid; p < bend; p += 256) {
        float2 rec = dstpart[p];
        unsigned pk = __float_as_uint(rec.y);
        int pos = atomicAdd(&hist[pk & LMASK], 1);
        csr[pos] = make_float2(rec.x, __int_as_float((int)(pk >> LBITS)));
    }
}

// ---------------------------------------------------------------------------
// K5: hs[n,:] = (A[n,:] @ W_emb + b_emb) * inv_sqrt_out[n], padded rows
// ---------------------------------------------------------------------------
__global__ void k_embed(const float* __restrict__ A,
                        const float* __restrict__ Wemb,
                        const float* __restrict__ bemb,
                        const float* __restrict__ inv_out,
                        float* __restrict__ hs) {
    __shared__ float sW[FIN * WID];
    __shared__ float sb[WID];
    for (int i = threadIdx.x; i < FIN * WID; i += blockDim.x) sW[i] = Wemb[i];
    if (threadIdx.x < WID) sb[threadIdx.x] = bemb[threadIdx.x];
    __syncthreads();

    int n = blockIdx.x * blockDim.x + threadIdx.x;
    if (n >= NNODES) return;

    float acc[WID];
#pragma unroll
    for (int k = 0; k < WID; k++) acc[k] = sb[k];

    const float4* row4 = reinterpret_cast<const float4*>(A + (size_t)n * FIN);
#pragma unroll
    for (int f4 = 0; f4 < FIN / 4; f4++) {
        float4 v = row4[f4];
        int f = f4 * 4;
#pragma unroll
        for (int k = 0; k < WID; k++) acc[k] += v.x * sW[(f + 0) * WID + k];
#pragma unroll
        for (int k = 0; k < WID; k++) acc[k] += v.y * sW[(f + 1) * WID + k];
#pragma unroll
        for (int k = 0; k < WID; k++) acc[k] += v.z * sW[(f + 2) * WID + k];
#pragma unroll
        for (int k = 0; k < WID; k++) acc[k] += v.w * sW[(f + 3) * WID + k];
    }

    float sc = inv_out[n];
    float* out = hs + (size_t)n * HPAD;
    float4 o0 = make_float4(acc[0] * sc, acc[1] * sc, acc[2] * sc, acc[3] * sc);
    float4 o1 = make_float4(acc[4] * sc, acc[5] * sc, acc[6] * sc, acc[7] * sc);
    float2 o2 = make_float2(acc[8] * sc, acc[9] * sc);
    *reinterpret_cast<float4*>(out + 0) = o0;
    *reinterpret_cast<float4*>(out + 4) = o1;
    *reinterpret_cast<float2*>(out + 8) = o2;
}

// ---------------------------------------------------------------------------
// K7: pull-mode aggregate of gconv1 FUSED with node update + gconv2 proj.
// Rows are src-chunk-ordered -> hs gather window stays L2-resident.
// ---------------------------------------------------------------------------
__global__ void k_agg1(const float2* __restrict__ csr,
                       const int* __restrict__ row_ptr,
                       const float* __restrict__ hs,
                       const float* __restrict__ W1,
                       const float* __restrict__ b1,
                       const float* __restrict__ W2,
                       const float* __restrict__ inv_in,
                       const float* __restrict__ inv_out,
                       float* __restrict__ sproj) {
    __shared__ float sW1[WID * WID];
    __shared__ float sb1[WID];
    __shared__ float sW2[WID];
    for (int i = threadIdx.x; i < WID * WID; i += blockDim.x) sW1[i] = W1[i];
    if (threadIdx.x < WID) {
        sb1[threadIdx.x] = b1[threadIdx.x];
        sW2[threadIdx.x] = W2[threadIdx.x];
    }
    __syncthreads();

    int n = blockIdx.x * blockDim.x + threadIdx.x;
    if (n >= NNODES) return;

    int start = row_ptr[n];
    int end = (n == NNODES - 1) ? NEDGES : row_ptr[n + 1];

    float acc[WID];
#pragma unroll
    for (int k = 0; k < WID; k++) acc[k] = 0.0f;

    for (int p = start; p < end; p++) {
        float2 c2 = csr[p];
        float w = c2.x;
        int s = __float_as_int(c2.y);
        const float* hrow = hs + (size_t)s * HPAD;
        float4 a = *reinterpret_cast<const float4*>(hrow + 0);
        float4 b = *reinterpret_cast<const float4*>(hrow + 4);
        float2 c = *reinterpret_cast<const float2*>(hrow + 8);
        acc[0] += w * a.x; acc[1] += w * a.y; acc[2] += w * a.z; acc[3] += w * a.w;
        acc[4] += w * b.x; acc[5] += w * b.y; acc[6] += w * b.z; acc[7] += w * b.w;
        acc[8] += w * c.x; acc[9] += w * c.y;
    }

    float ii = inv_in[n];
    float dot = 0.0f;
#pragma unroll
    for (int j = 0; j < WID; j++) {
        float y = 0.0f;
#pragma unroll
        for (int k = 0; k < WID; k++) y += acc[k] * sW1[k * WID + j];
        y = y * ii + sb1[j];
        y = y > 0.0f ? y : 0.0f;
        dot += y * sW2[j];
    }
    sproj[n] = dot * inv_out[n];
}

// ---------------------------------------------------------------------------
// K8: pull-mode scalar aggregate of gconv2 FUSED with graph pooling.
// NOTE: __shfl_down clamps out-of-range lanes to SELF on AMD -> guard with
// lane + off < 64 (round-2 bug).
// ---------------------------------------------------------------------------
__global__ void k_agg2_pool(const float2* __restrict__ csr,
                            const int* __restrict__ row_ptr,
                            const float* __restrict__ sproj,
                            const float* __restrict__ inv_in,
                            const float* __restrict__ b2,
                            const int* __restrict__ graph_ids,
                            float* __restrict__ pooled) {
    int n = blockIdx.x * blockDim.x + threadIdx.x;
    int lane = threadIdx.x & 63;

    float v = 0.0f;
    int g = -1;
    if (n < NNODES) {
        int start = row_ptr[n];
        int end = (n == NNODES - 1) ? NEDGES : row_ptr[n + 1];
        float sum = 0.0f;
        for (int p = start; p < end; p++) {
            float2 c2 = csr[p];
            sum += c2.x * sproj[__float_as_int(c2.y)];
        }
        v = sum * inv_in[n] + b2[0];
        g = graph_ids[n];
    }

#pragma unroll
    for (int off = 1; off < 64; off <<= 1) {
        float vv = __shfl_down(v, off, 64);
        int gg = __shfl_down(g, off, 64);
        if (lane + off < 64 && gg == g) v += vv;
    }
    int gprev = __shfl_up(g, 1, 64);
    bool head = (lane == 0) || (gprev != g);
    if (g >= 0 && head) atomicAdd(&pooled[g], v);
}

// ---------------------------------------------------------------------------
// K9: out[g] = pooled[g] / count(g); counts via binary search on sorted gids
// ---------------------------------------------------------------------------
__global__ void k_final(const float* __restrict__ pooled,
                        const int* __restrict__ gids,
                        float* __restrict__ out) {
    int g = blockIdx.x * blockDim.x + threadIdx.x;
    if (g >= NGRAPHS) return;
    int lo = 0, hi = NNODES;
    while (lo < hi) { int m = (lo + hi) >> 1; if (gids[m] < g) lo = m + 1; else hi = m; }
    int first = lo;
    hi = NNODES;
    while (lo < hi) { int m = (lo + hi) >> 1; if (gids[m] < g + 1) lo = m + 1; else hi = m; }
    int cnt = lo - first;
    out[g] = pooled[g] / (float)(cnt > 0 ? cnt : 1);
}

// ---------------------------------------------------------------------------
extern "C" void kernel_launch(void* const* d_in, const int* in_sizes, int n_in,
                              void* d_out, int out_size, void* d_ws, size_t ws_size,
                              hipStream_t stream) {
    const float* atom = (const float*)d_in[0];
    const float* r    = (const float*)d_in[1];
    const float* Wemb = (const float*)d_in[2];
    const float* bemb = (const float*)d_in[3];
    const float* W1   = (const float*)d_in[4];
    const float* b1   = (const float*)d_in[5];
    const float* W2   = (const float*)d_in[6];
    const float* b2   = (const float*)d_in[7];
    const int*   src  = (const int*)d_in[8];
    const int*   dst  = (const int*)d_in[9];
    const int*   gids = (const int*)d_in[10];
    float* out = (float*)d_out;

    // Workspace layout (16B-aligned chunks), ~130 MB total.
    char* w = (char*)d_ws;
    float* pooled  = (float*)w;  w += (size_t)NGRAPHS * 4;          // zeroed (2 KB)
    int*   cnt     = (int*)w;    w += (size_t)CNT_N * 4;            // 5.6 MB (scan layout)
    int*   cntT    = (int*)w;    w += (size_t)CNT_N * 4;            // 5.6 MB (k-major)
    int*   partial = (int*)w;    w += (size_t)((SBLKS + 3) & ~3) * 4;
    int*   row_ptr = (int*)w;    w += (size_t)((NNODES + 4) & ~3) * 4;
    float* inv_in  = (float*)w;  w += (size_t)NNODES * 4;
    float* inv_out = (float*)w;  w += (size_t)NNODES * 4;
    float* sproj   = (float*)w;  w += (size_t)NNODES * 4;
    float* hs      = (float*)w;  w += (size_t)NNODES * HPAD * 4;    // 12.8 MB
    float2* dstpart = (float2*)w; w += (size_t)NEDGES * 8;          // 51.2 MB
    float2* csr     = (float2*)w; w += (size_t)NEDGES * 8;          // 51.2 MB
    // srcpart aliases csr: dead before k_bucket_csr writes csr
    unsigned short* srcpart = (unsigned short*)csr;                 // 12.8 MB view

    hipMemsetAsync(pooled, 0, (size_t)NGRAPHS * 4, stream);

    const int B = 256;

    k_part_count<<<PBLK, B, 0, stream>>>(src, dst, cntT);
    k_transpose<<<dim3((CELLS + 31) / 32, (PBLK + 31) / 32), dim3(32, 8), 0, stream>>>(
        cntT, cnt, PBLK, CELLS);   // [512][2744] -> [2744][512]
    k_scan_partial<<<SBLKS, B, 0, stream>>>(cnt, partial);
    k_scan_top<<<1, 1024, 0, stream>>>(partial);
    k_scan_apply<<<SBLKS, B, 0, stream>>>(cnt, partial);
    k_transpose<<<dim3((PBLK + 31) / 32, (CELLS + 31) / 32), dim3(32, 8), 0, stream>>>(
        cnt, cntT, CELLS, PBLK);   // scanned [2744][512] -> [512][2744]
    k_part_scatter<<<PBLK, B, 0, stream>>>(r, src, dst, cntT, dstpart, srcpart);
    k_bucket_odeg<<<NB, B, 0, stream>>>(srcpart, cnt, inv_out);   // before csr write (alias)
    k_bucket_csr<<<NB, B, 0, stream>>>(dstpart, cnt, csr, row_ptr, inv_in);
    k_embed<<<NBLK, B, 0, stream>>>(atom, Wemb, bemb, inv_out, hs);
    k_agg1<<<NBLK, B, 0, stream>>>(csr, row_ptr, hs, W1, b1, W2, inv_in, inv_out, sproj);
    k_agg2_pool<<<NBLK, B, 0, stream>>>(csr, row_ptr, sproj, inv_in, b2, gids, pooled);
    k_final<<<(NGRAPHS + B - 1) / B, B, 0, stream>>>(pooled, gids, out);
}

// Round 7
// 805.909 us; speedup vs baseline: 1.1524x; 1.1524x over previous
//
#include <hip/hip_runtime.h>
#include <math.h>

#define NNODES  200000
#define NEDGES  6400000
#define NGRAPHS 512
#define FIN     92
#define WID     10
#define HPAD    16                     // hs row padded to 16 floats (64 B)
#define NBLK    ((NNODES + 255) / 256) // 782

// partition geometry
#define LBITS   10
#define LSIZE   1024                   // dst nodes per bucket
#define LMASK   (LSIZE - 1)
#define NB      196                    // ceil(200000/1024) buckets
#define PBLK    512                    // partition blocks
#define EPB     (NEDGES / PBLK)        // 12500 edges per partition block (exact)
#define TILE    2500                   // staging tile (EPB = 5 * TILE exactly)
#define NTILE   (EPB / TILE)           // 5
#define CELLS   (2 * NB)               // 392 (dst plane + src plane)
#define CNT_N   (CELLS * PBLK)         // 200,704 scan elements
#define SBLKS   (CNT_N / 256)          // 784 scan blocks (exact)

// chunk-ordered rows (for k_agg1 gather locality)
#define CHBITS  14
#define NCHK    13                     // ceil(200000/16384) src chunks
#define KEYS    (LSIZE * NCHK)         // 13312 sort keys per bucket
#define KPT     (KEYS / 256)           // 52 keys per thread in the scan

// ---------------------------------------------------------------------------
// P1: per-(bucket,block) counts via LDS histograms. ZERO global atomics.
// ---------------------------------------------------------------------------
__global__ void k_part_count(const int* __restrict__ src,
                             const int* __restrict__ dst,
                             int* __restrict__ cnt) {
    __shared__ int hD[NB];
    __shared__ int hS[NB];
    int tid = threadIdx.x, k = blockIdx.x;
    if (tid < NB) { hD[tid] = 0; hS[tid] = 0; }
    __syncthreads();
    int base = k * EPB;
    for (int i = tid; i < EPB; i += 256) {
        int e = base + i;
        atomicAdd(&hD[dst[e] >> LBITS], 1);
        atomicAdd(&hS[src[e] >> LBITS], 1);
    }
    __syncthreads();
    if (tid < NB) {
        cnt[tid * PBLK + k] = hD[tid];
        cnt[(NB + tid) * PBLK + k] = hS[tid];
    }
}

// ---------------------------------------------------------------------------
// Scan step 1: per-block (256-elem) partial sums of cnt
// ---------------------------------------------------------------------------
__global__ void k_scan_partial(const int* __restrict__ cnt,
                               int* __restrict__ partial) {
    __shared__ int sdata[256];
    int tid = threadIdx.x;
    sdata[tid] = cnt[blockIdx.x * 256 + tid];
    __syncthreads();
    for (int s = 128; s > 0; s >>= 1) {
        if (tid < s) sdata[tid] += sdata[tid + s];
        __syncthreads();
    }
    if (tid == 0) partial[blockIdx.x] = sdata[0];
}

// ---------------------------------------------------------------------------
// Scan step 2: single-block exclusive scan of the 784 partials
// ---------------------------------------------------------------------------
__global__ void k_scan_top(int* __restrict__ partial) {
    __shared__ int buf[1024];
    __shared__ int carry_s;
    if (threadIdx.x == 0) carry_s = 0;
    __syncthreads();
    for (int base = 0; base < SBLKS; base += 1024) {
        int i = base + threadIdx.x;
        int c = carry_s;
        int orig = (i < SBLKS) ? partial[i] : 0;
        buf[threadIdx.x] = orig;
        __syncthreads();
        for (int off = 1; off < 1024; off <<= 1) {
            int t = (threadIdx.x >= off) ? buf[threadIdx.x - off] : 0;
            __syncthreads();
            buf[threadIdx.x] += t;
            __syncthreads();
        }
        if (i < SBLKS) partial[i] = buf[threadIdx.x] - orig + c;
        __syncthreads();
        if (threadIdx.x == 0) carry_s = c + buf[1023];
        __syncthreads();
    }
}

// ---------------------------------------------------------------------------
// Scan step 3: apply -- in-place exclusive scan of cnt
// ---------------------------------------------------------------------------
__global__ void k_scan_apply(int* __restrict__ cnt,
                             const int* __restrict__ partial) {
    __shared__ int buf[256];
    int tid = threadIdx.x;
    int i = blockIdx.x * 256 + tid;
    int v = cnt[i];
    buf[tid] = v;
    __syncthreads();
    for (int off = 1; off < 256; off <<= 1) {
        int t = (tid >= off) ? buf[tid - off] : 0;
        __syncthreads();
        buf[tid] += t;
        __syncthreads();
    }
    cnt[i] = buf[tid] - v + partial[blockIdx.x];
}

// ---------------------------------------------------------------------------
// P2: TILE-STAGED scatter. Per 2500-edge tile: LDS hist -> LDS scan ->
// snapshot global cursors -> place records cell-ordered in LDS staging with
// precomputed destinations -> coalesced copy-out (consecutive threads write
// consecutive addresses within each cell segment). ZERO global atomics, and
// no isolated 8 B scattered stores (round-6's 5x write amplification).
// ---------------------------------------------------------------------------
__global__ void k_part_scatter(const float* __restrict__ r,
                               const int* __restrict__ src,
                               const int* __restrict__ dst,
                               const int* __restrict__ cnt,
                               float2* __restrict__ dstpart,
                               unsigned short* __restrict__ srcpart) {
    __shared__ int curD[NB], curS[NB];     // running global cursors
    __shared__ int hD[NB], hS[NB];         // tile hist, then tile cursor
    __shared__ int baseD[NB], baseS[NB];   // tile-local exclusive base
    __shared__ int segD[NB], segS[NB];     // global cursor snapshot at tile start
    __shared__ int sbuf[256];
    __shared__ float2 stD[TILE];           // 20 KB staged dst records
    __shared__ int    ddD[TILE];           // 10 KB their global slots
    __shared__ unsigned short stS[TILE];   // 5 KB staged src locals
    __shared__ int    ddS[TILE];           // 10 KB their global slots

    int tid = threadIdx.x, k = blockIdx.x;
    if (tid < NB) {
        curD[tid] = cnt[tid * PBLK + k];
        curS[tid] = cnt[(NB + tid) * PBLK + k] - NEDGES;
    }
    __syncthreads();

    int base = k * EPB;
    for (int t = 0; t < NTILE; t++) {
        int tbase = base + t * TILE;
        if (tid < NB) { hD[tid] = 0; hS[tid] = 0; }
        __syncthreads();
        // pass A: tile histograms
        for (int i = tid; i < TILE; i += 256) {
            int e = tbase + i;
            atomicAdd(&hD[dst[e] >> LBITS], 1);
            atomicAdd(&hS[src[e] >> LBITS], 1);
        }
        __syncthreads();
        // scan hD -> baseD; snapshot/advance global cursors
        int v = (tid < NB) ? hD[tid] : 0;
        sbuf[tid] = v;
        __syncthreads();
        for (int off = 1; off < 256; off <<= 1) {
            int tv = (tid >= off) ? sbuf[tid - off] : 0;
            __syncthreads();
            sbuf[tid] += tv;
            __syncthreads();
        }
        if (tid < NB) { baseD[tid] = sbuf[tid] - v; segD[tid] = curD[tid]; }
        __syncthreads();
        int v2 = (tid < NB) ? hS[tid] : 0;
        sbuf[tid] = v2;
        __syncthreads();
        for (int off = 1; off < 256; off <<= 1) {
            int tv = (tid >= off) ? sbuf[tid - off] : 0;
            __syncthreads();
            sbuf[tid] += tv;
            __syncthreads();
        }
        if (tid < NB) {
            baseS[tid] = sbuf[tid] - v2;
            segS[tid] = curS[tid];
            curD[tid] += hD[tid];
            curS[tid] += hS[tid];
            hD[tid] = baseD[tid];   // reuse as tile cursor
            hS[tid] = baseS[tid];
        }
        __syncthreads();
        // pass B: stage records cell-ordered, precompute global destinations
        for (int i = tid; i < TILE; i += 256) {
            int e = tbase + i;
            int s = src[e], d = dst[e];
            float x = r[3 * e + 0];
            float y = r[3 * e + 1];
            float z = r[3 * e + 2];
            float w = expf(-(x * x + y * y + z * z));
            int cd = d >> LBITS;
            int idx = atomicAdd(&hD[cd], 1);
            stD[idx] = make_float2(w, __int_as_float((s << LBITS) | (d & LMASK)));
            ddD[idx] = segD[cd] + (idx - baseD[cd]);
            int cs = s >> LBITS;
            int ids = atomicAdd(&hS[cs], 1);
            stS[ids] = (unsigned short)(s & LMASK);
            ddS[ids] = segS[cs] + (ids - baseS[cs]);
        }
        __syncthreads();
        // pass C: coalesced copy-out
        for (int i = tid; i < TILE; i += 256) {
            dstpart[ddD[i]] = stD[i];
            srcpart[ddS[i]] = stS[i];
        }
        __syncthreads();
    }
}

// ---------------------------------------------------------------------------
// P3s: per-bucket out-degree histogram (LDS) -> inv_sqrt_out.
// Runs BEFORE k_bucket_csr because srcpart aliases the csr region.
// ---------------------------------------------------------------------------
__global__ void k_bucket_odeg(const unsigned short* __restrict__ srcpart,
                              const int* __restrict__ cnt,
                              float* __restrict__ inv_out) {
    __shared__ int hist[LSIZE];
    int tid = threadIdx.x, b = blockIdx.x;
    int bstart = cnt[(NB + b) * PBLK] - NEDGES;
    int bend = (b == NB - 1) ? NEDGES : (cnt[(NB + b + 1) * PBLK] - NEDGES);
    for (int l = tid; l < LSIZE; l += 256) hist[l] = 0;
    __syncthreads();
    for (int p = bstart + tid; p < bend; p += 256)
        atomicAdd(&hist[srcpart[p]], 1);
    __syncthreads();
    for (int l = tid; l < LSIZE; l += 256) {
        int n = (b << LBITS) + l;
        if (n < NNODES) {
            int c = hist[l];
            inv_out[n] = rsqrtf((float)(c < 1 ? 1 : c));
        }
    }
}

// ---------------------------------------------------------------------------
// P3d: per-bucket CSR build with joint key (local*13 + srcChunk): counting
// sort gives rows contiguous AND src-chunk-ordered within each row (k_agg1's
// gather window stays L2-resident). 53 KB LDS histogram; each block writes
// only its own bucket segment (no cross-block line sharing).
// ---------------------------------------------------------------------------
__global__ void k_bucket_csr(const float2* __restrict__ dstpart,
                             const int* __restrict__ cnt,
                             float2* __restrict__ csr,
                             int* __restrict__ row_ptr,
                             float* __restrict__ inv_in) {
    __shared__ int hist[KEYS];   // 53,248 B
    __shared__ int sbuf[256];
    int tid = threadIdx.x, b = blockIdx.x;
    int bstart = cnt[b * PBLK];
    int bend = cnt[(b + 1) * PBLK];   // b==NB-1 reads first src-plane elem == NEDGES

    for (int j = tid; j < KEYS; j += 256) hist[j] = 0;
    __syncthreads();
    // count: key = local*NCHK + chunk  (chunk = src>>14 = pk>>24)
    for (int p = bstart + tid; p < bend; p += 256) {
        unsigned pk = __float_as_uint(dstpart[p].y);
        atomicAdd(&hist[(pk & LMASK) * NCHK + (pk >> 24)], 1);
    }
    __syncthreads();
    // exclusive scan over the 13312 keys (52/thread sequential + block scan)
    int kb = tid * KPT;
    int sum = 0;
    for (int j = 0; j < KPT; j++) sum += hist[kb + j];
    sbuf[tid] = sum;
    __syncthreads();
    for (int off = 1; off < 256; off <<= 1) {
        int tv = (tid >= off) ? sbuf[tid - off] : 0;
        __syncthreads();
        sbuf[tid] += tv;
        __syncthreads();
    }
    int run = sbuf[tid] - sum + bstart;   // global cursor for this thread's keys
    for (int j = 0; j < KPT; j++) {       // own-range only: no race
        int c = hist[kb + j];
        hist[kb + j] = run;
        run += c;
    }
    __syncthreads();
    // rows: start = cursor at key l*NCHK (read BEFORE placement mutates)
    for (int l = tid; l < LSIZE; l += 256) {
        int rs = hist[l * NCHK];
        int re = (l == LSIZE - 1) ? bend : hist[(l + 1) * NCHK];
        int n = (b << LBITS) + l;
        if (n < NNODES) {
            row_ptr[n] = rs;
            int c = re - rs;
            inv_in[n] = rsqrtf((float)(c < 1 ? 1 : c));
        }
    }
    __syncthreads();
    // placement
    for (int p = bstart + tid; p < bend; p += 256) {
        float2 rec = dstpart[p];
        unsigned pk = __float_as_uint(rec.y);
        int pos = atomicAdd(&hist[(pk & LMASK) * NCHK + (pk >> 24)], 1);
        csr[pos] = make_float2(rec.x, __int_as_float((int)(pk >> LBITS)));
    }
}

// ---------------------------------------------------------------------------
// K5: hs[n,:] = (A[n,:] @ W_emb + b_emb) * inv_sqrt_out[n], padded rows
// ---------------------------------------------------------------------------
__global__ void k_embed(const float* __restrict__ A,
                        const float* __restrict__ Wemb,
                        const float* __restrict__ bemb,
                        const float* __restrict__ inv_out,
                        float* __restrict__ hs) {
    __shared__ float sW[FIN * WID];
    __shared__ float sb[WID];
    for (int i = threadIdx.x; i < FIN * WID; i += blockDim.x) sW[i] = Wemb[i];
    if (threadIdx.x < WID) sb[threadIdx.x] = bemb[threadIdx.x];
    __syncthreads();

    int n = blockIdx.x * blockDim.x + threadIdx.x;
    if (n >= NNODES) return;

    float acc[WID];
#pragma unroll
    for (int k = 0; k < WID; k++) acc[k] = sb[k];

    const float4* row4 = reinterpret_cast<const float4*>(A + (size_t)n * FIN);
#pragma unroll
    for (int f4 = 0; f4 < FIN / 4; f4++) {
        float4 v = row4[f4];
        int f = f4 * 4;
#pragma unroll
        for (int k = 0; k < WID; k++) acc[k] += v.x * sW[(f + 0) * WID + k];
#pragma unroll
        for (int k = 0; k < WID; k++) acc[k] += v.y * sW[(f + 1) * WID + k];
#pragma unroll
        for (int k = 0; k < WID; k++) acc[k] += v.z * sW[(f + 2) * WID + k];
#pragma unroll
        for (int k = 0; k < WID; k++) acc[k] += v.w * sW[(f + 3) * WID + k];
    }

    float sc = inv_out[n];
    float* out = hs + (size_t)n * HPAD;
    float4 o0 = make_float4(acc[0] * sc, acc[1] * sc, acc[2] * sc, acc[3] * sc);
    float4 o1 = make_float4(acc[4] * sc, acc[5] * sc, acc[6] * sc, acc[7] * sc);
    float2 o2 = make_float2(acc[8] * sc, acc[9] * sc);
    *reinterpret_cast<float4*>(out + 0) = o0;
    *reinterpret_cast<float4*>(out + 4) = o1;
    *reinterpret_cast<float2*>(out + 8) = o2;
}

// ---------------------------------------------------------------------------
// K7: pull-mode aggregate of gconv1 FUSED with node update + gconv2 proj.
// Rows are src-chunk-ordered -> hs gather window stays L2-resident.
// ---------------------------------------------------------------------------
__global__ void k_agg1(const float2* __restrict__ csr,
                       const int* __restrict__ row_ptr,
                       const float* __restrict__ hs,
                       const float* __restrict__ W1,
                       const float* __restrict__ b1,
                       const float* __restrict__ W2,
                       const float* __restrict__ inv_in,
                       const float* __restrict__ inv_out,
                       float* __restrict__ sproj) {
    __shared__ float sW1[WID * WID];
    __shared__ float sb1[WID];
    __shared__ float sW2[WID];
    for (int i = threadIdx.x; i < WID * WID; i += blockDim.x) sW1[i] = W1[i];
    if (threadIdx.x < WID) {
        sb1[threadIdx.x] = b1[threadIdx.x];
        sW2[threadIdx.x] = W2[threadIdx.x];
    }
    __syncthreads();

    int n = blockIdx.x * blockDim.x + threadIdx.x;
    if (n >= NNODES) return;

    int start = row_ptr[n];
    int end = (n == NNODES - 1) ? NEDGES : row_ptr[n + 1];

    float acc[WID];
#pragma unroll
    for (int k = 0; k < WID; k++) acc[k] = 0.0f;

    for (int p = start; p < end; p++) {
        float2 c2 = csr[p];
        float w = c2.x;
        int s = __float_as_int(c2.y);
        const float* hrow = hs + (size_t)s * HPAD;
        float4 a = *reinterpret_cast<const float4*>(hrow + 0);
        float4 b = *reinterpret_cast<const float4*>(hrow + 4);
        float2 c = *reinterpret_cast<const float2*>(hrow + 8);
        acc[0] += w * a.x; acc[1] += w * a.y; acc[2] += w * a.z; acc[3] += w * a.w;
        acc[4] += w * b.x; acc[5] += w * b.y; acc[6] += w * b.z; acc[7] += w * b.w;
        acc[8] += w * c.x; acc[9] += w * c.y;
    }

    float ii = inv_in[n];
    float dot = 0.0f;
#pragma unroll
    for (int j = 0; j < WID; j++) {
        float y = 0.0f;
#pragma unroll
        for (int k = 0; k < WID; k++) y += acc[k] * sW1[k * WID + j];
        y = y * ii + sb1[j];
        y = y > 0.0f ? y : 0.0f;
        dot += y * sW2[j];
    }
    sproj[n] = dot * inv_out[n];
}

// ---------------------------------------------------------------------------
// K8: pull-mode scalar aggregate of gconv2 FUSED with graph pooling.
// NOTE: __shfl_down clamps out-of-range lanes to SELF on AMD -> guard with
// lane + off < 64 (round-2 bug).
// ---------------------------------------------------------------------------
__global__ void k_agg2_pool(const float2* __restrict__ csr,
                            const int* __restrict__ row_ptr,
                            const float* __restrict__ sproj,
                            const float* __restrict__ inv_in,
                            const float* __restrict__ b2,
                            const int* __restrict__ graph_ids,
                            float* __restrict__ pooled) {
    int n = blockIdx.x * blockDim.x + threadIdx.x;
    int lane = threadIdx.x & 63;

    float v = 0.0f;
    int g = -1;
    if (n < NNODES) {
        int start = row_ptr[n];
        int end = (n == NNODES - 1) ? NEDGES : row_ptr[n + 1];
        float sum = 0.0f;
        for (int p = start; p < end; p++) {
            float2 c2 = csr[p];
            sum += c2.x * sproj[__float_as_int(c2.y)];
        }
        v = sum * inv_in[n] + b2[0];
        g = graph_ids[n];
    }

#pragma unroll
    for (int off = 1; off < 64; off <<= 1) {
        float vv = __shfl_down(v, off, 64);
        int gg = __shfl_down(g, off, 64);
        if (lane + off < 64 && gg == g) v += vv;
    }
    int gprev = __shfl_up(g, 1, 64);
    bool head = (lane == 0) || (gprev != g);
    if (g >= 0 && head) atomicAdd(&pooled[g], v);
}

// ---------------------------------------------------------------------------
// K9: out[g] = pooled[g] / count(g); counts via binary search on sorted gids
// ---------------------------------------------------------------------------
__global__ void k_final(const float* __restrict__ pooled,
                        const int* __restrict__ gids,
                        float* __restrict__ out) {
    int g = blockIdx.x * blockDim.x + threadIdx.x;
    if (g >= NGRAPHS) return;
    int lo = 0, hi = NNODES;
    while (lo < hi) { int m = (lo + hi) >> 1; if (gids[m] < g) lo = m + 1; else hi = m; }
    int first = lo;
    hi = NNODES;
    while (lo < hi) { int m = (lo + hi) >> 1; if (gids[m] < g + 1) lo = m + 1; else hi = m; }
    int cnt = lo - first;
    out[g] = pooled[g] / (float)(cnt > 0 ? cnt : 1);
}

// ---------------------------------------------------------------------------
extern "C" void kernel_launch(void* const* d_in, const int* in_sizes, int n_in,
                              void* d_out, int out_size, void* d_ws, size_t ws_size,
                              hipStream_t stream) {
    const float* atom = (const float*)d_in[0];
    const float* r    = (const float*)d_in[1];
    const float* Wemb = (const float*)d_in[2];
    const float* bemb = (const float*)d_in[3];
    const float* W1   = (const float*)d_in[4];
    const float* b1   = (const float*)d_in[5];
    const float* W2   = (const float*)d_in[6];
    const float* b2   = (const float*)d_in[7];
    const int*   src  = (const int*)d_in[8];
    const int*   dst  = (const int*)d_in[9];
    const int*   gids = (const int*)d_in[10];
    float* out = (float*)d_out;

    // Workspace layout (16B-aligned chunks), ~120 MB total.
    char* w = (char*)d_ws;
    float* pooled  = (float*)w;  w += (size_t)NGRAPHS * 4;          // zeroed (2 KB)
    int*   cnt     = (int*)w;    w += (size_t)CNT_N * 4;            // 0.8 MB
    int*   partial = (int*)w;    w += (size_t)((SBLKS + 3) & ~3) * 4;
    int*   row_ptr = (int*)w;    w += (size_t)((NNODES + 4) & ~3) * 4;
    float* inv_in  = (float*)w;  w += (size_t)NNODES * 4;
    float* inv_out = (float*)w;  w += (size_t)NNODES * 4;
    float* sproj   = (float*)w;  w += (size_t)NNODES * 4;
    float* hs      = (float*)w;  w += (size_t)NNODES * HPAD * 4;    // 12.8 MB
    float2* dstpart = (float2*)w; w += (size_t)NEDGES * 8;          // 51.2 MB
    float2* csr     = (float2*)w; w += (size_t)NEDGES * 8;          // 51.2 MB
    // srcpart aliases csr: dead before k_bucket_csr writes csr
    unsigned short* srcpart = (unsigned short*)csr;                 // 12.8 MB view

    hipMemsetAsync(pooled, 0, (size_t)NGRAPHS * 4, stream);

    const int B = 256;

    k_part_count<<<PBLK, B, 0, stream>>>(src, dst, cnt);
    k_scan_partial<<<SBLKS, B, 0, stream>>>(cnt, partial);
    k_scan_top<<<1, 1024, 0, stream>>>(partial);
    k_scan_apply<<<SBLKS, B, 0, stream>>>(cnt, partial);
    k_part_scatter<<<PBLK, B, 0, stream>>>(r, src, dst, cnt, dstpart, srcpart);
    k_bucket_odeg<<<NB, B, 0, stream>>>(srcpart, cnt, inv_out);   // before csr write (alias)
    k_bucket_csr<<<NB, B, 0, stream>>>(dstpart, cnt, csr, row_ptr, inv_in);
    k_embed<<<NBLK, B, 0, stream>>>(atom, Wemb, bemb, inv_out, hs);
    k_agg1<<<NBLK, B, 0, stream>>>(csr, row_ptr, hs, W1, b1, W2, inv_in, inv_out, sproj);
    k_agg2_pool<<<NBLK, B, 0, stream>>>(csr, row_ptr, sproj, inv_in, b2, gids, pooled);
    k_final<<<(NGRAPHS + B - 1) / B, B, 0, stream>>>(pooled, gids, out);
}

// Round 8
// 789.375 us; speedup vs baseline: 1.1765x; 1.0209x over previous
//
#include <hip/hip_runtime.h>
#include <math.h>

#define NNODES  200000
#define NEDGES  6400000
#define NGRAPHS 512
#define FIN     92
#define WID     10
#define HPAD    16                     // hs row padded to 16 floats (64 B)
#define NBLK    ((NNODES + 255) / 256) // 782

// partition geometry
#define LBITS   10
#define LSIZE   1024                   // dst nodes per bucket
#define LMASK   (LSIZE - 1)
#define NB      196                    // ceil(200000/1024) buckets
#define PBLK    512                    // partition blocks
#define EPB     (NEDGES / PBLK)        // 12500 edges per partition block (exact)
#define TILE    2500                   // staging tile (EPB = 5 * TILE exactly)
#define NTILE   (EPB / TILE)           // 5
#define CELLS   (2 * NB)               // 392 (dst plane + src plane)
#define CNT_N   (CELLS * PBLK)         // 200,704 scan elements
#define SBLKS   (CNT_N / 256)          // 784 scan blocks (exact)

// chunk-ordered rows (for k_agg1 gather locality)
#define CHBITS  14
#define NCHK    13                     // ceil(200000/16384) src chunks
#define KEYS    (LSIZE * NCHK)         // 13312 sort keys per bucket
#define KPT     (KEYS / 256)           // 52 keys per thread in the scan

// ---------------------------------------------------------------------------
// P1: per-(bucket,block) counts via LDS histograms. ZERO global atomics.
// ---------------------------------------------------------------------------
__global__ void k_part_count(const int* __restrict__ src,
                             const int* __restrict__ dst,
                             int* __restrict__ cnt) {
    __shared__ int hD[NB];
    __shared__ int hS[NB];
    int tid = threadIdx.x, k = blockIdx.x;
    if (tid < NB) { hD[tid] = 0; hS[tid] = 0; }
    __syncthreads();
    int base = k * EPB;
    for (int i = tid; i < EPB; i += 256) {
        int e = base + i;
        atomicAdd(&hD[dst[e] >> LBITS], 1);
        atomicAdd(&hS[src[e] >> LBITS], 1);
    }
    __syncthreads();
    if (tid < NB) {
        cnt[tid * PBLK + k] = hD[tid];
        cnt[(NB + tid) * PBLK + k] = hS[tid];
    }
}

// ---------------------------------------------------------------------------
// Scan step 1: per-block (256-elem) partial sums of cnt
// ---------------------------------------------------------------------------
__global__ void k_scan_partial(const int* __restrict__ cnt,
                               int* __restrict__ partial) {
    __shared__ int sdata[256];
    int tid = threadIdx.x;
    sdata[tid] = cnt[blockIdx.x * 256 + tid];
    __syncthreads();
    for (int s = 128; s > 0; s >>= 1) {
        if (tid < s) sdata[tid] += sdata[tid + s];
        __syncthreads();
    }
    if (tid == 0) partial[blockIdx.x] = sdata[0];
}

// ---------------------------------------------------------------------------
// Scan step 2: single-block exclusive scan of the 784 partials
// ---------------------------------------------------------------------------
__global__ void k_scan_top(int* __restrict__ partial) {
    __shared__ int buf[1024];
    __shared__ int carry_s;
    if (threadIdx.x == 0) carry_s = 0;
    __syncthreads();
    for (int base = 0; base < SBLKS; base += 1024) {
        int i = base + threadIdx.x;
        int c = carry_s;
        int orig = (i < SBLKS) ? partial[i] : 0;
        buf[threadIdx.x] = orig;
        __syncthreads();
        for (int off = 1; off < 1024; off <<= 1) {
            int t = (threadIdx.x >= off) ? buf[threadIdx.x - off] : 0;
            __syncthreads();
            buf[threadIdx.x] += t;
            __syncthreads();
        }
        if (i < SBLKS) partial[i] = buf[threadIdx.x] - orig + c;
        __syncthreads();
        if (threadIdx.x == 0) carry_s = c + buf[1023];
        __syncthreads();
    }
}

// ---------------------------------------------------------------------------
// Scan step 3: apply -- in-place exclusive scan of cnt
// ---------------------------------------------------------------------------
__global__ void k_scan_apply(int* __restrict__ cnt,
                             const int* __restrict__ partial) {
    __shared__ int buf[256];
    int tid = threadIdx.x;
    int i = blockIdx.x * 256 + tid;
    int v = cnt[i];
    buf[tid] = v;
    __syncthreads();
    for (int off = 1; off < 256; off <<= 1) {
        int t = (tid >= off) ? buf[tid - off] : 0;
        __syncthreads();
        buf[tid] += t;
        __syncthreads();
    }
    cnt[i] = buf[tid] - v + partial[blockIdx.x];
}

// ---------------------------------------------------------------------------
// P2: TILE-STAGED scatter. Per 2500-edge tile: LDS hist -> LDS scan ->
// snapshot global cursors -> place records cell-ordered in LDS staging with
// precomputed destinations -> coalesced copy-out. ZERO global atomics.
// ---------------------------------------------------------------------------
__global__ void k_part_scatter(const float* __restrict__ r,
                               const int* __restrict__ src,
                               const int* __restrict__ dst,
                               const int* __restrict__ cnt,
                               float2* __restrict__ dstpart,
                               unsigned short* __restrict__ srcpart) {
    __shared__ int curD[NB], curS[NB];     // running global cursors
    __shared__ int hD[NB], hS[NB];         // tile hist, then tile cursor
    __shared__ int baseD[NB], baseS[NB];   // tile-local exclusive base
    __shared__ int segD[NB], segS[NB];     // global cursor snapshot at tile start
    __shared__ int sbuf[256];
    __shared__ float2 stD[TILE];           // 20 KB staged dst records
    __shared__ int    ddD[TILE];           // 10 KB their global slots
    __shared__ unsigned short stS[TILE];   // 5 KB staged src locals
    __shared__ int    ddS[TILE];           // 10 KB their global slots

    int tid = threadIdx.x, k = blockIdx.x;
    if (tid < NB) {
        curD[tid] = cnt[tid * PBLK + k];
        curS[tid] = cnt[(NB + tid) * PBLK + k] - NEDGES;
    }
    __syncthreads();

    int base = k * EPB;
    for (int t = 0; t < NTILE; t++) {
        int tbase = base + t * TILE;
        if (tid < NB) { hD[tid] = 0; hS[tid] = 0; }
        __syncthreads();
        // pass A: tile histograms
        for (int i = tid; i < TILE; i += 256) {
            int e = tbase + i;
            atomicAdd(&hD[dst[e] >> LBITS], 1);
            atomicAdd(&hS[src[e] >> LBITS], 1);
        }
        __syncthreads();
        // scan hD -> baseD; snapshot/advance global cursors
        int v = (tid < NB) ? hD[tid] : 0;
        sbuf[tid] = v;
        __syncthreads();
        for (int off = 1; off < 256; off <<= 1) {
            int tv = (tid >= off) ? sbuf[tid - off] : 0;
            __syncthreads();
            sbuf[tid] += tv;
            __syncthreads();
        }
        if (tid < NB) { baseD[tid] = sbuf[tid] - v; segD[tid] = curD[tid]; }
        __syncthreads();
        int v2 = (tid < NB) ? hS[tid] : 0;
        sbuf[tid] = v2;
        __syncthreads();
        for (int off = 1; off < 256; off <<= 1) {
            int tv = (tid >= off) ? sbuf[tid - off] : 0;
            __syncthreads();
            sbuf[tid] += tv;
            __syncthreads();
        }
        if (tid < NB) {
            baseS[tid] = sbuf[tid] - v2;
            segS[tid] = curS[tid];
            curD[tid] += hD[tid];
            curS[tid] += hS[tid];
            hD[tid] = baseD[tid];   // reuse as tile cursor
            hS[tid] = baseS[tid];
        }
        __syncthreads();
        // pass B: stage records cell-ordered, precompute global destinations
        for (int i = tid; i < TILE; i += 256) {
            int e = tbase + i;
            int s = src[e], d = dst[e];
            float x = r[3 * e + 0];
            float y = r[3 * e + 1];
            float z = r[3 * e + 2];
            float w = expf(-(x * x + y * y + z * z));
            int cd = d >> LBITS;
            int idx = atomicAdd(&hD[cd], 1);
            stD[idx] = make_float2(w, __int_as_float((s << LBITS) | (d & LMASK)));
            ddD[idx] = segD[cd] + (idx - baseD[cd]);
            int cs = s >> LBITS;
            int ids = atomicAdd(&hS[cs], 1);
            stS[ids] = (unsigned short)(s & LMASK);
            ddS[ids] = segS[cs] + (ids - baseS[cs]);
        }
        __syncthreads();
        // pass C: coalesced copy-out
        for (int i = tid; i < TILE; i += 256) {
            dstpart[ddD[i]] = stD[i];
            srcpart[ddS[i]] = stS[i];
        }
        __syncthreads();
    }
}

// ---------------------------------------------------------------------------
// P3s: per-bucket out-degree histogram (LDS) -> inv_sqrt_out.
// Runs BEFORE k_bucket_csr because srcpart aliases the csr region.
// ---------------------------------------------------------------------------
__global__ void k_bucket_odeg(const unsigned short* __restrict__ srcpart,
                              const int* __restrict__ cnt,
                              float* __restrict__ inv_out) {
    __shared__ int hist[LSIZE];
    int tid = threadIdx.x, b = blockIdx.x;
    int bstart = cnt[(NB + b) * PBLK] - NEDGES;
    int bend = (b == NB - 1) ? NEDGES : (cnt[(NB + b + 1) * PBLK] - NEDGES);
    for (int l = tid; l < LSIZE; l += 256) hist[l] = 0;
    __syncthreads();
    for (int p = bstart + tid; p < bend; p += 256)
        atomicAdd(&hist[srcpart[p]], 1);
    __syncthreads();
    for (int l = tid; l < LSIZE; l += 256) {
        int n = (b << LBITS) + l;
        if (n < NNODES) {
            int c = hist[l];
            inv_out[n] = rsqrtf((float)(c < 1 ? 1 : c));
        }
    }
}

// ---------------------------------------------------------------------------
// P3d: per-bucket CSR build with joint key (local*13 + srcChunk): counting
// sort gives rows contiguous AND src-chunk-ordered within each row.
// ---------------------------------------------------------------------------
__global__ void k_bucket_csr(const float2* __restrict__ dstpart,
                             const int* __restrict__ cnt,
                             float2* __restrict__ csr,
                             int* __restrict__ row_ptr,
                             float* __restrict__ inv_in) {
    __shared__ int hist[KEYS];   // 53,248 B
    __shared__ int sbuf[256];
    int tid = threadIdx.x, b = blockIdx.x;
    int bstart = cnt[b * PBLK];
    int bend = cnt[(b + 1) * PBLK];   // b==NB-1 reads first src-plane elem == NEDGES

    for (int j = tid; j < KEYS; j += 256) hist[j] = 0;
    __syncthreads();
    // count: key = local*NCHK + chunk  (chunk = src>>14 = pk>>24)
    for (int p = bstart + tid; p < bend; p += 256) {
        unsigned pk = __float_as_uint(dstpart[p].y);
        atomicAdd(&hist[(pk & LMASK) * NCHK + (pk >> 24)], 1);
    }
    __syncthreads();
    // exclusive scan over the 13312 keys (52/thread sequential + block scan)
    int kb = tid * KPT;
    int sum = 0;
    for (int j = 0; j < KPT; j++) sum += hist[kb + j];
    sbuf[tid] = sum;
    __syncthreads();
    for (int off = 1; off < 256; off <<= 1) {
        int tv = (tid >= off) ? sbuf[tid - off] : 0;
        __syncthreads();
        sbuf[tid] += tv;
        __syncthreads();
    }
    int run = sbuf[tid] - sum + bstart;   // global cursor for this thread's keys
    for (int j = 0; j < KPT; j++) {       // own-range only: no race
        int c = hist[kb + j];
        hist[kb + j] = run;
        run += c;
    }
    __syncthreads();
    // rows: start = cursor at key l*NCHK (read BEFORE placement mutates)
    for (int l = tid; l < LSIZE; l += 256) {
        int rs = hist[l * NCHK];
        int re = (l == LSIZE - 1) ? bend : hist[(l + 1) * NCHK];
        int n = (b << LBITS) + l;
        if (n < NNODES) {
            row_ptr[n] = rs;
            int c = re - rs;
            inv_in[n] = rsqrtf((float)(c < 1 ? 1 : c));
        }
    }
    __syncthreads();
    // placement
    for (int p = bstart + tid; p < bend; p += 256) {
        float2 rec = dstpart[p];
        unsigned pk = __float_as_uint(rec.y);
        int pos = atomicAdd(&hist[(pk & LMASK) * NCHK + (pk >> 24)], 1);
        csr[pos] = make_float2(rec.x, __int_as_float((int)(pk >> LBITS)));
    }
}

// ---------------------------------------------------------------------------
// K5: hs[n,:] = (A[n,:] @ W_emb + b_emb) * inv_sqrt_out[n], padded rows
// ---------------------------------------------------------------------------
__global__ void k_embed(const float* __restrict__ A,
                        const float* __restrict__ Wemb,
                        const float* __restrict__ bemb,
                        const float* __restrict__ inv_out,
                        float* __restrict__ hs) {
    __shared__ float sW[FIN * WID];
    __shared__ float sb[WID];
    for (int i = threadIdx.x; i < FIN * WID; i += blockDim.x) sW[i] = Wemb[i];
    if (threadIdx.x < WID) sb[threadIdx.x] = bemb[threadIdx.x];
    __syncthreads();

    int n = blockIdx.x * blockDim.x + threadIdx.x;
    if (n >= NNODES) return;

    float acc[WID];
#pragma unroll
    for (int k = 0; k < WID; k++) acc[k] = sb[k];

    const float4* row4 = reinterpret_cast<const float4*>(A + (size_t)n * FIN);
#pragma unroll
    for (int f4 = 0; f4 < FIN / 4; f4++) {
        float4 v = row4[f4];
        int f = f4 * 4;
#pragma unroll
        for (int k = 0; k < WID; k++) acc[k] += v.x * sW[(f + 0) * WID + k];
#pragma unroll
        for (int k = 0; k < WID; k++) acc[k] += v.y * sW[(f + 1) * WID + k];
#pragma unroll
        for (int k = 0; k < WID; k++) acc[k] += v.z * sW[(f + 2) * WID + k];
#pragma unroll
        for (int k = 0; k < WID; k++) acc[k] += v.w * sW[(f + 3) * WID + k];
    }

    float sc = inv_out[n];
    float* out = hs + (size_t)n * HPAD;
    float4 o0 = make_float4(acc[0] * sc, acc[1] * sc, acc[2] * sc, acc[3] * sc);
    float4 o1 = make_float4(acc[4] * sc, acc[5] * sc, acc[6] * sc, acc[7] * sc);
    float2 o2 = make_float2(acc[8] * sc, acc[9] * sc);
    *reinterpret_cast<float4*>(out + 0) = o0;
    *reinterpret_cast<float4*>(out + 4) = o1;
    *reinterpret_cast<float2*>(out + 8) = o2;
}

// ---------------------------------------------------------------------------
// K7: pull-mode aggregate of gconv1 FUSED with node update + gconv2 proj.
// PHASE-LOCKED chunk walk: outer loop over the 13 src chunks, block barrier
// between chunks. All lanes stay within one chunk at a time -> the hs gather
// window per XCD is ~1 chunk (1 MB) instead of the unsynchronized 4 MB+
// (round-7: per-thread walk rate = 13/degree => intra-wave chunk divergence;
// FETCH stayed at 531 MB). No early return: barrier requires all threads.
// ---------------------------------------------------------------------------
__global__ void k_agg1(const float2* __restrict__ csr,
                       const int* __restrict__ row_ptr,
                       const float* __restrict__ hs,
                       const float* __restrict__ W1,
                       const float* __restrict__ b1,
                       const float* __restrict__ W2,
                       const float* __restrict__ inv_in,
                       const float* __restrict__ inv_out,
                       float* __restrict__ sproj) {
    __shared__ float sW1[WID * WID];
    __shared__ float sb1[WID];
    __shared__ float sW2[WID];
    for (int i = threadIdx.x; i < WID * WID; i += blockDim.x) sW1[i] = W1[i];
    if (threadIdx.x < WID) {
        sb1[threadIdx.x] = b1[threadIdx.x];
        sW2[threadIdx.x] = W2[threadIdx.x];
    }
    __syncthreads();

    int n = blockIdx.x * blockDim.x + threadIdx.x;
    bool valid = (n < NNODES);
    int start = 0, end = 0;
    if (valid) {
        start = row_ptr[n];
        end = (n == NNODES - 1) ? NEDGES : row_ptr[n + 1];
    }

    float acc[WID];
#pragma unroll
    for (int k = 0; k < WID; k++) acc[k] = 0.0f;

    int p = start;
    for (int c = 0; c < NCHK; c++) {
        int slim = (c + 1) << CHBITS;
        while (p < end) {
            float2 c2 = csr[p];
            int s = __float_as_int(c2.y);
            if (s >= slim) break;
            float w = c2.x;
            const float* hrow = hs + (size_t)s * HPAD;
            float4 a = *reinterpret_cast<const float4*>(hrow + 0);
            float4 b = *reinterpret_cast<const float4*>(hrow + 4);
            float2 cc = *reinterpret_cast<const float2*>(hrow + 8);
            acc[0] += w * a.x; acc[1] += w * a.y; acc[2] += w * a.z; acc[3] += w * a.w;
            acc[4] += w * b.x; acc[5] += w * b.y; acc[6] += w * b.z; acc[7] += w * b.w;
            acc[8] += w * cc.x; acc[9] += w * cc.y;
            p++;
        }
        __syncthreads();   // phase barrier: whole block advances chunk together
    }
    // drain (should be empty: chunk 12 covers all src < 13*16384)
    for (; p < end; p++) {
        float2 c2 = csr[p];
        float w = c2.x;
        int s = __float_as_int(c2.y);
        const float* hrow = hs + (size_t)s * HPAD;
        float4 a = *reinterpret_cast<const float4*>(hrow + 0);
        float4 b = *reinterpret_cast<const float4*>(hrow + 4);
        float2 cc = *reinterpret_cast<const float2*>(hrow + 8);
        acc[0] += w * a.x; acc[1] += w * a.y; acc[2] += w * a.z; acc[3] += w * a.w;
        acc[4] += w * b.x; acc[5] += w * b.y; acc[6] += w * b.z; acc[7] += w * b.w;
        acc[8] += w * cc.x; acc[9] += w * cc.y;
    }

    if (!valid) return;

    float ii = inv_in[n];
    float dot = 0.0f;
#pragma unroll
    for (int j = 0; j < WID; j++) {
        float y = 0.0f;
#pragma unroll
        for (int k = 0; k < WID; k++) y += acc[k] * sW1[k * WID + j];
        y = y * ii + sb1[j];
        y = y > 0.0f ? y : 0.0f;
        dot += y * sW2[j];
    }
    sproj[n] = dot * inv_out[n];
}

// ---------------------------------------------------------------------------
// K8: pull-mode scalar aggregate of gconv2 FUSED with graph pooling.
// NOTE: __shfl_down clamps out-of-range lanes to SELF on AMD -> guard with
// lane + off < 64 (round-2 bug).
// ---------------------------------------------------------------------------
__global__ void k_agg2_pool(const float2* __restrict__ csr,
                            const int* __restrict__ row_ptr,
                            const float* __restrict__ sproj,
                            const float* __restrict__ inv_in,
                            const float* __restrict__ b2,
                            const int* __restrict__ graph_ids,
                            float* __restrict__ pooled) {
    int n = blockIdx.x * blockDim.x + threadIdx.x;
    int lane = threadIdx.x & 63;

    float v = 0.0f;
    int g = -1;
    if (n < NNODES) {
        int start = row_ptr[n];
        int end = (n == NNODES - 1) ? NEDGES : row_ptr[n + 1];
        float sum = 0.0f;
        for (int p = start; p < end; p++) {
            float2 c2 = csr[p];
            sum += c2.x * sproj[__float_as_int(c2.y)];
        }
        v = sum * inv_in[n] + b2[0];
        g = graph_ids[n];
    }

#pragma unroll
    for (int off = 1; off < 64; off <<= 1) {
        float vv = __shfl_down(v, off, 64);
        int gg = __shfl_down(g, off, 64);
        if (lane + off < 64 && gg == g) v += vv;
    }
    int gprev = __shfl_up(g, 1, 64);
    bool head = (lane == 0) || (gprev != g);
    if (g >= 0 && head) atomicAdd(&pooled[g], v);
}

// ---------------------------------------------------------------------------
// K9: out[g] = pooled[g] / count(g); counts via binary search on sorted gids
// ---------------------------------------------------------------------------
__global__ void k_final(const float* __restrict__ pooled,
                        const int* __restrict__ gids,
                        float* __restrict__ out) {
    int g = blockIdx.x * blockDim.x + threadIdx.x;
    if (g >= NGRAPHS) return;
    int lo = 0, hi = NNODES;
    while (lo < hi) { int m = (lo + hi) >> 1; if (gids[m] < g) lo = m + 1; else hi = m; }
    int first = lo;
    hi = NNODES;
    while (lo < hi) { int m = (lo + hi) >> 1; if (gids[m] < g + 1) lo = m + 1; else hi = m; }
    int cnt = lo - first;
    out[g] = pooled[g] / (float)(cnt > 0 ? cnt : 1);
}

// ---------------------------------------------------------------------------
extern "C" void kernel_launch(void* const* d_in, const int* in_sizes, int n_in,
                              void* d_out, int out_size, void* d_ws, size_t ws_size,
                              hipStream_t stream) {
    const float* atom = (const float*)d_in[0];
    const float* r    = (const float*)d_in[1];
    const float* Wemb = (const float*)d_in[2];
    const float* bemb = (const float*)d_in[3];
    const float* W1   = (const float*)d_in[4];
    const float* b1   = (const float*)d_in[5];
    const float* W2   = (const float*)d_in[6];
    const float* b2   = (const float*)d_in[7];
    const int*   src  = (const int*)d_in[8];
    const int*   dst  = (const int*)d_in[9];
    const int*   gids = (const int*)d_in[10];
    float* out = (float*)d_out;

    // Workspace layout (16B-aligned chunks), ~120 MB total.
    char* w = (char*)d_ws;
    float* pooled  = (float*)w;  w += (size_t)NGRAPHS * 4;          // zeroed (2 KB)
    int*   cnt     = (int*)w;    w += (size_t)CNT_N * 4;            // 0.8 MB
    int*   partial = (int*)w;    w += (size_t)((SBLKS + 3) & ~3) * 4;
    int*   row_ptr = (int*)w;    w += (size_t)((NNODES + 4) & ~3) * 4;
    float* inv_in  = (float*)w;  w += (size_t)NNODES * 4;
    float* inv_out = (float*)w;  w += (size_t)NNODES * 4;
    float* sproj   = (float*)w;  w += (size_t)NNODES * 4;
    float* hs      = (float*)w;  w += (size_t)NNODES * HPAD * 4;    // 12.8 MB
    float2* dstpart = (float2*)w; w += (size_t)NEDGES * 8;          // 51.2 MB
    float2* csr     = (float2*)w; w += (size_t)NEDGES * 8;          // 51.2 MB
    // srcpart aliases csr: dead before k_bucket_csr writes csr
    unsigned short* srcpart = (unsigned short*)csr;                 // 12.8 MB view

    hipMemsetAsync(pooled, 0, (size_t)NGRAPHS * 4, stream);

    const int B = 256;

    k_part_count<<<PBLK, B, 0, stream>>>(src, dst, cnt);
    k_scan_partial<<<SBLKS, B, 0, stream>>>(cnt, partial);
    k_scan_top<<<1, 1024, 0, stream>>>(partial);
    k_scan_apply<<<SBLKS, B, 0, stream>>>(cnt, partial);
    k_part_scatter<<<PBLK, B, 0, stream>>>(r, src, dst, cnt, dstpart, srcpart);
    k_bucket_odeg<<<NB, B, 0, stream>>>(srcpart, cnt, inv_out);   // before csr write (alias)
    k_bucket_csr<<<NB, B, 0, stream>>>(dstpart, cnt, csr, row_ptr, inv_in);
    k_embed<<<NBLK, B, 0, stream>>>(atom, Wemb, bemb, inv_out, hs);
    k_agg1<<<NBLK, B, 0, stream>>>(csr, row_ptr, hs, W1, b1, W2, inv_in, inv_out, sproj);
    k_agg2_pool<<<NBLK, B, 0, stream>>>(csr, row_ptr, sproj, inv_in, b2, gids, pooled);
    k_final<<<(NGRAPHS + B - 1) / B, B, 0, stream>>>(pooled, gids, out);
}